// Round 6
// baseline (550.189 us; speedup 1.0000x reference)
//
#include <hip/hip_runtime.h>
#include <math.h>

#define BATCH 2048
#define IN_F 256
#define OUT_F 256
#define DEG 8

typedef __attribute__((ext_vector_type(4))) float f4;

// ---------- workspace layout (floats) ----------
// ws[0..63]   : per-block partial mins
// ws[64..127] : per-block partial maxs
// ws[128]     : a  (scale:  xs = a*x + c)
// ws[129]     : c  (offset: c = -a*xmin - 1)
// ws[256 ..]  : base_out (2048 x 256 fp32 = 2 MB)

// ---------------- min/max over whole x tensor ----------------
__global__ __launch_bounds__(256) void k_minmax_partial(const float* __restrict__ x,
                                                        float* __restrict__ ws) {
    int t = threadIdx.x;
    int blk = blockIdx.x;          // 64 blocks
    const f4* x4 = (const f4*)x;   // 131072 float4 total; 2048/block; 8/thread
    float mn = 1e30f, mx = -1e30f;
    int base = blk * 2048 + t;
#pragma unroll
    for (int j = 0; j < 8; ++j) {
        f4 v = x4[base + j * 256];
        mn = fminf(mn, fminf(fminf(v.x, v.y), fminf(v.z, v.w)));
        mx = fmaxf(mx, fmaxf(fmaxf(v.x, v.y), fmaxf(v.z, v.w)));
    }
#pragma unroll
    for (int off = 32; off > 0; off >>= 1) {
        mn = fminf(mn, __shfl_down(mn, off));
        mx = fmaxf(mx, __shfl_down(mx, off));
    }
    __shared__ float smn[4], smx[4];
    if ((t & 63) == 0) { smn[t >> 6] = mn; smx[t >> 6] = mx; }
    __syncthreads();
    if (t == 0) {
        mn = fminf(fminf(smn[0], smn[1]), fminf(smn[2], smn[3]));
        mx = fmaxf(fmaxf(smx[0], smx[1]), fmaxf(smx[2], smx[3]));
        ws[blk] = mn;
        ws[64 + blk] = mx;
    }
}

__global__ void k_minmax_final(float* __restrict__ ws) {
    int t = threadIdx.x;  // 64 threads, 1 wave
    float mn = ws[t], mx = ws[64 + t];
#pragma unroll
    for (int off = 32; off > 0; off >>= 1) {
        mn = fminf(mn, __shfl_down(mn, off));
        mx = fmaxf(mx, __shfl_down(mx, off));
    }
    if (t == 0) {
        float a = 2.0f / (mx - mn);
        ws[128] = a;
        ws[129] = -a * mn - 1.0f;
    }
}

// ---------------- base_out = swish(x) @ base_weight ----------------
// grid (64, 4): 32-batch x 64-out tile per block, 256 threads, 2x4 per thread.
#define KC 64
__global__ __launch_bounds__(256) void k_base(const float* __restrict__ x,
                                              const float* __restrict__ w,
                                              float* __restrict__ basews) {
    __shared__ float As[32][KC + 1];   // +1 pad breaks bank conflicts
    __shared__ float Bs[KC][64];
    int t = threadIdx.x;
    int b0 = blockIdx.x * 32;
    int o0 = blockIdx.y * 64;
    int to = t & 15;   // o quad: o = o0 + to*4 .. +3
    int tb = t >> 4;   // b pair: b = b0 + 2*tb, +1
    f4 acc0 = {0.f, 0.f, 0.f, 0.f}, acc1 = {0.f, 0.f, 0.f, 0.f};
    for (int kc = 0; kc < IN_F; kc += KC) {
        __syncthreads();
        // A tile: 32 x 64, swish applied on load. 512 float4, 2/thread.
#pragma unroll
        for (int j = 0; j < 2; ++j) {
            int e = t + 256 * j;
            int b = e >> 4;
            int k4 = e & 15;
            f4 v = ((const f4*)(x + (size_t)(b0 + b) * IN_F + kc))[k4];
            v.x = v.x / (1.0f + __expf(-v.x));
            v.y = v.y / (1.0f + __expf(-v.y));
            v.z = v.z / (1.0f + __expf(-v.z));
            v.w = v.w / (1.0f + __expf(-v.w));
            As[b][k4 * 4 + 0] = v.x;
            As[b][k4 * 4 + 1] = v.y;
            As[b][k4 * 4 + 2] = v.z;
            As[b][k4 * 4 + 3] = v.w;
        }
        // B tile: 64 x 64. 1024 float4, 4/thread.
#pragma unroll
        for (int j = 0; j < 4; ++j) {
            int e = t + 256 * j;
            int k = e >> 4;
            int o4 = e & 15;
            f4 v = ((const f4*)(w + (size_t)(kc + k) * OUT_F + o0))[o4];
            *((f4*)&Bs[k][o4 * 4]) = v;
        }
        __syncthreads();
#pragma unroll 8
        for (int k = 0; k < KC; ++k) {
            float a0 = As[2 * tb][k];      // broadcast across 16 lanes
            float a1 = As[2 * tb + 1][k];
            f4 bv = *((const f4*)&Bs[k][to * 4]);
            acc0 += a0 * bv;
            acc1 += a1 * bv;
        }
    }
    float* dst = basews + (size_t)(b0 + 2 * tb) * OUT_F + o0 + to * 4;
    *((f4*)dst) = acc0;
    *((f4*)(dst + OUT_F)) = acc1;
}

// ---------------- main: out[b][i][o] = base[b][o] + sum_d T_d(xs[b][i]) * cw[i][o][d] ----
// RESTRUCTURED (R1): one WAVE owns one full output row out[b][i][0:256].
// Lane l owns o = 4l..4l+3 -> every nt store is one contiguous 1 KB row segment
// (was: 4x256B disjoint segments per wave). Each wave handles 2 rows (ia, ib)
// to reuse the 1 KB base-row load. Weights (2x32 floats) live in VGPRs,
// reused across 32 batches. No LDS, no syncs.
// grid (IN_F/8, BATCH/32) = (32, 64), 256 threads (4 waves).
__global__ __launch_bounds__(256) void k_main(const float* __restrict__ x,
                                              const float* __restrict__ cw,
                                              const float* __restrict__ basews,
                                              const float* __restrict__ scl,
                                              float* __restrict__ out) {
    int t = threadIdx.x;
    int l = t & 63;    // lane: owns o = 4l..4l+3
    int wv = t >> 6;   // wave 0..3
    int i0 = blockIdx.x * 8;
    int b0 = blockIdx.y * 32;
    int ia = i0 + 2 * wv;
    int ib = ia + 1;
    float a = scl[0];
    float c = scl[1];

    // cw[i][o][d], d innermost: lane's slice for row i is 32 consecutive
    // floats at cw + i*2048 + l*32  ->  8 f4 loads per row, once per 32 batches.
    const f4* wpa = (const f4*)(cw + (size_t)ia * (OUT_F * DEG) + (size_t)l * 32);
    const f4* wpb = (const f4*)(cw + (size_t)ib * (OUT_F * DEG) + (size_t)l * 32);
    float wa[32], wb[32];  // [o_local*8 + d] -> constant-indexed, stays in VGPRs
#pragma unroll
    for (int j = 0; j < 8; ++j) {
        f4 va = wpa[j];
        wa[4 * j + 0] = va.x; wa[4 * j + 1] = va.y;
        wa[4 * j + 2] = va.z; wa[4 * j + 3] = va.w;
        f4 vb = wpb[j];
        wb[4 * j + 0] = vb.x; wb[4 * j + 1] = vb.y;
        wb[4 * j + 2] = vb.z; wb[4 * j + 3] = vb.w;
    }

    const float* xpa = x + (size_t)b0 * IN_F + ia;        // wave-uniform addr
    const float* xpb = x + (size_t)b0 * IN_F + ib;
    const f4* bp = (const f4*)(basews + (size_t)b0 * OUT_F) + l;   // 1 KB/wave
    f4* opa = (f4*)(out + ((size_t)b0 * IN_F + ia) * OUT_F) + l;
    f4* opb = (f4*)(out + ((size_t)b0 * IN_F + ib) * OUT_F) + l;

#pragma unroll 2
    for (int bb = 0; bb < 32; ++bb) {
        float xva = xpa[(size_t)bb * IN_F];
        float xvb = xpb[(size_t)bb * IN_F];
        f4 base = bp[(size_t)bb * (OUT_F / 4)];

        float xsa = fmaf(a, xva, c);
        float xsb = fmaf(a, xvb, c);
        float Ta[8], Tb[8];
        Ta[0] = 1.0f; Ta[1] = xsa;
        Tb[0] = 1.0f; Tb[1] = xsb;
        float x2a = xsa + xsa;
        float x2b = xsb + xsb;
#pragma unroll
        for (int d = 2; d < DEG; ++d) {
            Ta[d] = fmaf(x2a, Ta[d - 1], -Ta[d - 2]);
            Tb[d] = fmaf(x2b, Tb[d - 1], -Tb[d - 2]);
        }

        f4 ra = base, rb = base;
#pragma unroll
        for (int d = 0; d < DEG; ++d) {
            ra.x = fmaf(Ta[d], wa[0 + d], ra.x);
            ra.y = fmaf(Ta[d], wa[8 + d], ra.y);
            ra.z = fmaf(Ta[d], wa[16 + d], ra.z);
            ra.w = fmaf(Ta[d], wa[24 + d], ra.w);
            rb.x = fmaf(Tb[d], wb[0 + d], rb.x);
            rb.y = fmaf(Tb[d], wb[8 + d], rb.y);
            rb.z = fmaf(Tb[d], wb[16 + d], rb.z);
            rb.w = fmaf(Tb[d], wb[24 + d], rb.w);
        }
        __builtin_nontemporal_store(ra, opa + (size_t)bb * (IN_F * OUT_F / 4));
        __builtin_nontemporal_store(rb, opb + (size_t)bb * (IN_F * OUT_F / 4));
    }
}

extern "C" void kernel_launch(void* const* d_in, const int* in_sizes, int n_in,
                              void* d_out, int out_size, void* d_ws, size_t ws_size,
                              hipStream_t stream) {
    (void)in_sizes; (void)n_in; (void)out_size; (void)ws_size;
    const float* x  = (const float*)d_in[0];
    const float* bw = (const float*)d_in[1];
    const float* cw = (const float*)d_in[2];
    float* out = (float*)d_out;
    float* ws = (float*)d_ws;
    float* scl = ws + 128;
    float* basews = ws + 256;

    k_minmax_partial<<<64, 256, 0, stream>>>(x, ws);
    k_minmax_final<<<1, 64, 0, stream>>>(ws);
    dim3 gb(BATCH / 32, OUT_F / 64);
    k_base<<<gb, 256, 0, stream>>>(x, bw, basews);
    dim3 gm(IN_F / 8, BATCH / 32);
    k_main<<<gm, 256, 0, stream>>>(x, cw, basews, scl, out);
}